// Round 4
// baseline (71.090 us; speedup 1.0000x reference)
//
#include <hip/hip_runtime.h>
#include <hip/hip_cooperative_groups.h>
#include <math.h>

namespace cg = cooperative_groups;

#define BATCH 16
#define NKER  16
#define KS    5
#define UNITS 10
#define HIN   28
#define HOUT  24       // 28-5+1
#define PO    12       // pooled 12x12
#define NPOOL (PO*PO)  // 144
#define NC    (KS*KS)  // 25 patch channels
#define PCOLS 26       // padded patch columns (c=25 is zero)
#define PART  112      // per-(b,k) partial: A[100] + mu4[10] + tr + mn

// One cooperative kernel: 256 blocks (one per (b,k)) do stage 1; grid sync;
// blocks 0..15 (one per b) do the tiny finale.
__global__ __launch_bounds__(256) void vdp_fused(
    const float* __restrict__ x,       // [B,1,28,28]
    const float* __restrict__ conv_w,  // [K,1,5,5]
    const float* __restrict__ conv_s,  // [K]
    const float* __restrict__ fc_w,    // [2304,10]
    const float* __restrict__ fc_s,    // [10]
    float* __restrict__ out,           // [B*10] p ++ [B*100] sigma_out
    float* __restrict__ ws)            // [B*K][PART]
{
    const int bk = blockIdx.x;
    const int b  = bk >> 4;
    const int k  = bk & 15;
    const int t  = threadIdx.x;

    __shared__ float xs[HIN*HIN];          // 784
    __shared__ float cw[NC];               // 25 (this k only)
    __shared__ float fcw_s[NPOOL*UNITS];   // 1440 (rows k*144..k*144+143)
    __shared__ float P_s[NPOOL*PCOLS];     // 3744: gated argmax patches
    __shared__ float T_s[UNITS*PCOLS];     // 260
    __shared__ float red_s[4][12];
    __shared__ float fin_s[12];            // [tr_raw, mn, mu4[10]]
    __shared__ float sp1s;
    // finale scratch (only blocks 0..15 touch these, after grid sync)
    __shared__ float s_[PART];
    __shared__ float s4[UNITS*UNITS];
    __shared__ float tmp[UNITS*UNITS];
    __shared__ float p_s[UNITS];
    __shared__ float r_s[UNITS];
    __shared__ float q_s[UNITS];
    __shared__ float sp2[UNITS];

    // ---- stage inputs (vectorized; bases 16B-aligned) ----
    {
        const float4* x4 = reinterpret_cast<const float4*>(x + b*HIN*HIN);
        float4* xs4 = reinterpret_cast<float4*>(xs);
        for (int i = t; i < HIN*HIN/4; i += 256) xs4[i] = x4[i];
        const float4* f4 = reinterpret_cast<const float4*>(fc_w + k*NPOOL*UNITS);
        float4* fs4 = reinterpret_cast<float4*>(fcw_s);
        for (int i = t; i < NPOOL*UNITS/4; i += 256) fs4[i] = f4[i];
        if (t < NC) cw[t] = conv_w[k*NC + t];
        if (t == 0) sp1s = log1pf(expf(conv_s[k]));
    }
    __syncthreads();

    // ---- phase 1: conv + relu + argmax-pool, one pooled cell per thread ----
    float v_tr = 0.f, v_mn = 0.f;
    float v_mu[UNITS];
    #pragma unroll
    for (int u = 0; u < UNITS; ++u) v_mu[u] = 0.f;

    if (t < NPOOL) {
        const int pi = t / PO, pj = t - pi*PO;
        float w6[36];                       // 6x6 window in registers
        #pragma unroll
        for (int r = 0; r < 6; ++r)
            #pragma unroll
            for (int cc = 0; cc < 6; ++cc)
                w6[r*6 + cc] = xs[(2*pi + r)*HIN + 2*pj + cc];
        float cwr[NC];
        #pragma unroll
        for (int c = 0; c < NC; ++c) cwr[c] = cw[c];

        float a0 = 0.f, a1 = 0.f, a2 = 0.f, a3 = 0.f;
        #pragma unroll
        for (int kh = 0; kh < KS; ++kh)
            #pragma unroll
            for (int kw = 0; kw < KS; ++kw) {
                const float w = cwr[kh*KS + kw];
                a0 = fmaf(w, w6[kh*6 + kw],       a0);
                a1 = fmaf(w, w6[kh*6 + kw + 1],   a1);
                a2 = fmaf(w, w6[(kh+1)*6 + kw],   a2);
                a3 = fmaf(w, w6[(kh+1)*6 + kw+1], a3);
            }
        const float r0 = fmaxf(a0, 0.f), r1 = fmaxf(a1, 0.f);
        const float r2 = fmaxf(a2, 0.f), r3 = fmaxf(a3, 0.f);
        float bestv = r0; int besta = 0;               // first-max wins (jnp.argmax)
        if (r1 > bestv) { bestv = r1; besta = 1; }
        if (r2 > bestv) { bestv = r2; besta = 2; }
        if (r3 > bestv) { bestv = r3; besta = 3; }
        const float mu3 = bestv;
        const float g   = (mu3 > 0.f) ? 1.f : 0.f;

        float ns = 0.f;
        #pragma unroll
        for (int kh = 0; kh < KS; ++kh)
            #pragma unroll
            for (int kw = 0; kw < KS; ++kw) {
                const float v0 = w6[kh*6 + kw];
                const float v1 = w6[kh*6 + kw + 1];
                const float v2 = w6[(kh+1)*6 + kw];
                const float v3 = w6[(kh+1)*6 + kw + 1];
                const float val = (besta < 2) ? ((besta == 0) ? v0 : v1)
                                              : ((besta == 2) ? v2 : v3);
                const float pv = g * val;
                P_s[t*PCOLS + kh*KS + kw] = pv;
                ns = fmaf(pv, pv, ns);                 // g * ||patch||^2
            }
        P_s[t*PCOLS + NC] = 0.f;
        v_tr = ns;
        v_mn = mu3*mu3;
        #pragma unroll
        for (int u = 0; u < UNITS; ++u) v_mu[u] = mu3*fcw_s[t*UNITS + u];
    }

    // ---- deterministic tree-reduce 12 values over the block ----
    {
        float vals[12];
        vals[0] = v_tr; vals[1] = v_mn;
        #pragma unroll
        for (int u = 0; u < UNITS; ++u) vals[2+u] = v_mu[u];
        #pragma unroll
        for (int off = 32; off >= 1; off >>= 1)
            #pragma unroll
            for (int j = 0; j < 12; ++j)
                vals[j] += __shfl_down(vals[j], off);
        const int wid = t >> 6, lane = t & 63;
        if (lane == 0)
            #pragma unroll
            for (int j = 0; j < 12; ++j) red_s[wid][j] = vals[j];
    }
    __syncthreads();
    if (t < 12) fin_s[t] = red_s[0][t] + red_s[1][t] + red_s[2][t] + red_s[3][t];

    // ---- phase 2: T[u,c] = sum_i fcw[i,u]*P[i,c] — 250 threads, 1 scalar each ----
    if (t < UNITS*NC) {
        const int u = t / NC, c = t - u*NC;
        float acc = 0.f;
        #pragma unroll 8
        for (int i = 0; i < NPOOL; ++i)
            acc = fmaf(fcw_s[i*UNITS + u], P_s[i*PCOLS + c], acc);
        T_s[u*PCOLS + c] = acc;
    }
    __syncthreads();

    // ---- phase 3: A[u,v] = sp1 * sum_c T[u,c]*T[v,c]; write 112 partials ----
    float* wsp = ws + bk*PART;
    if (t < UNITS*UNITS) {
        const int u = t / UNITS, v = t - u*UNITS;
        float s = 0.f;
        #pragma unroll
        for (int c = 0; c < NC; ++c) s = fmaf(T_s[u*PCOLS + c], T_s[v*PCOLS + c], s);
        wsp[t] = sp1s * s;
    } else if (t < UNITS*UNITS + UNITS) {
        wsp[t] = fin_s[2 + (t - UNITS*UNITS)];       // mu4 partial
    } else if (t == PART - 2) {
        wsp[PART-2] = sp1s * fin_s[0];               // tr partial (sp1 applied)
    } else if (t == PART - 1) {
        wsp[PART-1] = fin_s[1];                      // mnorm partial
    }

    // ---- grid-wide sync: partials visible device-wide ----
    __threadfence();
    cg::this_grid().sync();
    __threadfence();

    // ---- finale: blocks 0..15, one per batch element ----
    if (bk >= BATCH) return;
    const int bb = bk;

    if (t < PART) {
        float a = 0.f;
        #pragma unroll
        for (int kk = 0; kk < NKER; ++kk) a += ws[(bb*NKER + kk)*PART + t];
        s_[t] = a;
    }
    if (t < UNITS) sp2[t] = log1pf(expf(fc_s[t]));
    __syncthreads();

    if (t < UNITS*UNITS) {
        const int u = t / UNITS, v = t - u*UNITS;
        float a = s_[t];
        if (u == v) a += sp2[u]*(s_[PART-2] + s_[PART-1]);
        s4[t] = a;
    }
    if (t == 128) {   // softmax(mu4) on an idle lane
        float mx = s_[100];
        #pragma unroll
        for (int u = 1; u < UNITS; ++u) mx = fmaxf(mx, s_[100+u]);
        float sum = 0.f;
        float e[UNITS];
        #pragma unroll
        for (int u = 0; u < UNITS; ++u) { e[u] = expf(s_[100+u] - mx); sum += e[u]; }
        #pragma unroll
        for (int u = 0; u < UNITS; ++u) p_s[u] = e[u] / sum;
    }
    __syncthreads();

    // sigma_out = G s4 G^T with G = diag(p) - p p^T
    if (t < UNITS) {
        float r = 0.f;
        #pragma unroll
        for (int j = 0; j < UNITS; ++j) r = fmaf(p_s[j], s4[j*UNITS + t], r);
        r_s[t] = r;
    }
    __syncthreads();
    if (t < UNITS*UNITS) {
        const int i = t / UNITS, k2 = t - i*UNITS;
        tmp[t] = p_s[i]*(s4[t] - r_s[k2]);
    }
    __syncthreads();
    if (t < UNITS) {
        float q = 0.f;
        #pragma unroll
        for (int kk = 0; kk < UNITS; ++kk) q = fmaf(tmp[t*UNITS + kk], p_s[kk], q);
        q_s[t] = q;
    }
    __syncthreads();
    if (t < UNITS*UNITS) {
        const int i = t / UNITS, l = t - i*UNITS;
        out[BATCH*UNITS + bb*UNITS*UNITS + t] = p_s[l]*(tmp[i*UNITS + l] - q_s[i]);
    }
    if (t < UNITS) out[bb*UNITS + t] = p_s[t];
}

extern "C" void kernel_launch(void* const* d_in, const int* in_sizes, int n_in,
                              void* d_out, int out_size, void* d_ws, size_t ws_size,
                              hipStream_t stream) {
    const float* x      = (const float*)d_in[0];
    const float* conv_w = (const float*)d_in[1];
    const float* conv_s = (const float*)d_in[2];
    const float* fc_w   = (const float*)d_in[3];
    const float* fc_s   = (const float*)d_in[4];
    float* out = (float*)d_out;
    float* ws  = (float*)d_ws;   // BATCH*NKER*PART*4 = 114688 bytes

    void* args[] = { (void*)&x, (void*)&conv_w, (void*)&conv_s, (void*)&fc_w,
                     (void*)&fc_s, (void*)&out, (void*)&ws };
    hipLaunchCooperativeKernel((const void*)vdp_fused, dim3(BATCH*NKER), dim3(256),
                               args, 0, stream);
}

// Round 5
// 33.937 us; speedup vs baseline: 2.0948x; 2.0948x over previous
//
#include <hip/hip_runtime.h>
#include <math.h>

#define BATCH 16
#define NKER  16
#define KS    5
#define UNITS 10
#define HIN   28
#define HOUT  24       // 28-5+1
#define PO    12       // pooled 12x12
#define NPOOL (PO*PO)  // 144
#define NC    (KS*KS)  // 25 patch channels
#define PCOLS 26       // padded patch columns (c=25 is zero)
#define PART  112      // per-(b,k) partial: A[100] + mu4[10] + tr + mn
#define MAGIC 0x5a5a5a5au

// Single launch: 256 blocks, one per (b,k). Each produces its PART-float
// partial, release-stores a flag; blocks 0..15 acquire-spin on their 16 flags,
// then run the tiny finale for batch b. Flags are reset each call.
__global__ __launch_bounds__(256) void vdp_fused(
    const float* __restrict__ x,       // [B,1,28,28]
    const float* __restrict__ conv_w,  // [K,1,5,5]
    const float* __restrict__ conv_s,  // [K]
    const float* __restrict__ fc_w,    // [2304,10]
    const float* __restrict__ fc_s,    // [10]
    float* __restrict__ out,           // [B*10] p ++ [B*100] sigma_out
    float* __restrict__ ws,            // [256][PART]
    unsigned int* __restrict__ flags)  // [256]
{
    const int bk = blockIdx.x;
    const int b  = bk >> 4;
    const int k  = bk & 15;
    const int t  = threadIdx.x;

    __shared__ float xs[HIN*HIN];          // 784
    __shared__ float cw[NC];
    __shared__ float fcw_s[NPOOL*UNITS];   // 1440
    __shared__ float P_s[NPOOL*PCOLS];     // 3744
    __shared__ float T_s[UNITS*PCOLS];     // 260
    __shared__ float red_s[4][12];
    __shared__ float fin_s[12];
    __shared__ float sp1s;
    // finale scratch
    __shared__ float s_[PART];
    __shared__ float s4[UNITS*UNITS];
    __shared__ float tmp[UNITS*UNITS];
    __shared__ float p_s[UNITS];
    __shared__ float r_s[UNITS];
    __shared__ float q_s[UNITS];
    __shared__ float sp2[UNITS];

    // ---- stage inputs ----
    {
        const float4* x4 = reinterpret_cast<const float4*>(x + b*HIN*HIN);
        float4* xs4 = reinterpret_cast<float4*>(xs);
        for (int i = t; i < HIN*HIN/4; i += 256) xs4[i] = x4[i];
        const float4* f4 = reinterpret_cast<const float4*>(fc_w + k*NPOOL*UNITS);
        float4* fs4 = reinterpret_cast<float4*>(fcw_s);
        for (int i = t; i < NPOOL*UNITS/4; i += 256) fs4[i] = f4[i];
        if (t < NC) cw[t] = conv_w[k*NC + t];
        if (t == 0) sp1s = log1pf(expf(conv_s[k]));
    }
    __syncthreads();

    // ---- phase 1: conv + relu + argmax-pool ----
    float v_tr = 0.f, v_mn = 0.f;
    float v_mu[UNITS];
    #pragma unroll
    for (int u = 0; u < UNITS; ++u) v_mu[u] = 0.f;

    if (t < NPOOL) {
        const int pi = t / PO, pj = t - pi*PO;
        float w6[36];
        #pragma unroll
        for (int r = 0; r < 6; ++r)
            #pragma unroll
            for (int cc = 0; cc < 6; ++cc)
                w6[r*6 + cc] = xs[(2*pi + r)*HIN + 2*pj + cc];
        float cwr[NC];
        #pragma unroll
        for (int c = 0; c < NC; ++c) cwr[c] = cw[c];

        float a0 = 0.f, a1 = 0.f, a2 = 0.f, a3 = 0.f;
        #pragma unroll
        for (int kh = 0; kh < KS; ++kh)
            #pragma unroll
            for (int kw = 0; kw < KS; ++kw) {
                const float w = cwr[kh*KS + kw];
                a0 = fmaf(w, w6[kh*6 + kw],       a0);
                a1 = fmaf(w, w6[kh*6 + kw + 1],   a1);
                a2 = fmaf(w, w6[(kh+1)*6 + kw],   a2);
                a3 = fmaf(w, w6[(kh+1)*6 + kw+1], a3);
            }
        const float r0 = fmaxf(a0, 0.f), r1 = fmaxf(a1, 0.f);
        const float r2 = fmaxf(a2, 0.f), r3 = fmaxf(a3, 0.f);
        float bestv = r0; int besta = 0;               // first-max wins
        if (r1 > bestv) { bestv = r1; besta = 1; }
        if (r2 > bestv) { bestv = r2; besta = 2; }
        if (r3 > bestv) { bestv = r3; besta = 3; }
        const float mu3 = bestv;
        const float g   = (mu3 > 0.f) ? 1.f : 0.f;

        float ns = 0.f;
        #pragma unroll
        for (int kh = 0; kh < KS; ++kh)
            #pragma unroll
            for (int kw = 0; kw < KS; ++kw) {
                const float v0 = w6[kh*6 + kw];
                const float v1 = w6[kh*6 + kw + 1];
                const float v2 = w6[(kh+1)*6 + kw];
                const float v3 = w6[(kh+1)*6 + kw + 1];
                const float val = (besta < 2) ? ((besta == 0) ? v0 : v1)
                                              : ((besta == 2) ? v2 : v3);
                const float pv = g * val;
                P_s[t*PCOLS + kh*KS + kw] = pv;
                ns = fmaf(pv, pv, ns);
            }
        P_s[t*PCOLS + NC] = 0.f;
        v_tr = ns;
        v_mn = mu3*mu3;
        #pragma unroll
        for (int u = 0; u < UNITS; ++u) v_mu[u] = mu3*fcw_s[t*UNITS + u];
    }

    // ---- tree-reduce 12 values ----
    {
        float vals[12];
        vals[0] = v_tr; vals[1] = v_mn;
        #pragma unroll
        for (int u = 0; u < UNITS; ++u) vals[2+u] = v_mu[u];
        #pragma unroll
        for (int off = 32; off >= 1; off >>= 1)
            #pragma unroll
            for (int j = 0; j < 12; ++j)
                vals[j] += __shfl_down(vals[j], off);
        const int wid = t >> 6, lane = t & 63;
        if (lane == 0)
            #pragma unroll
            for (int j = 0; j < 12; ++j) red_s[wid][j] = vals[j];
    }
    __syncthreads();
    if (t < 12) fin_s[t] = red_s[0][t] + red_s[1][t] + red_s[2][t] + red_s[3][t];

    // ---- phase 2: T[u,c] = sum_i fcw[i,u]*P[i,c], split-i ILP ----
    if (t < UNITS*NC) {
        const int u = t / NC, c = t - u*NC;
        float acc0 = 0.f, acc1 = 0.f;
        #pragma unroll 8
        for (int i = 0; i < NPOOL/2; ++i) {
            acc0 = fmaf(fcw_s[i*UNITS + u],            P_s[i*PCOLS + c],            acc0);
            acc1 = fmaf(fcw_s[(i+NPOOL/2)*UNITS + u],  P_s[(i+NPOOL/2)*PCOLS + c],  acc1);
        }
        T_s[u*PCOLS + c] = acc0 + acc1;
    }
    __syncthreads();

    // ---- phase 3: write 112 partials ----
    float* wsp = ws + bk*PART;
    if (t < UNITS*UNITS) {
        const int u = t / UNITS, v = t - u*UNITS;
        float s = 0.f;
        #pragma unroll
        for (int c = 0; c < NC; ++c) s = fmaf(T_s[u*PCOLS + c], T_s[v*PCOLS + c], s);
        wsp[t] = sp1s * s;
    } else if (t < UNITS*UNITS + UNITS) {
        wsp[t] = fin_s[2 + (t - UNITS*UNITS)];
    } else if (t == PART - 2) {
        wsp[PART-2] = sp1s * fin_s[0];
    } else if (t == PART - 1) {
        wsp[PART-1] = fin_s[1];
    }

    // ---- publish: device-scope release flag ----
    __threadfence();          // prior partial stores visible agent-wide
    __syncthreads();          // whole block done writing
    if (t == 0)
        __hip_atomic_store(&flags[bk], MAGIC, __ATOMIC_RELEASE, __HIP_MEMORY_SCOPE_AGENT);

    // ---- finale: blocks 0..15, one per batch element ----
    if (bk >= BATCH) return;
    const int bb = bk;

    if (t < NKER) {
        while (__hip_atomic_load(&flags[bb*NKER + t], __ATOMIC_ACQUIRE,
                                 __HIP_MEMORY_SCOPE_AGENT) != MAGIC) { }
    }
    __syncthreads();
    __threadfence();          // acquire side: subsequent loads see partials

    if (t < PART) {
        float a = 0.f;
        #pragma unroll
        for (int kk = 0; kk < NKER; ++kk) a += ws[(bb*NKER + kk)*PART + t];
        s_[t] = a;
    }
    if (t < UNITS) sp2[t] = log1pf(expf(fc_s[t]));
    __syncthreads();
    // reset flags so every call is self-contained (poison-safe either way)
    if (t < NKER)
        __hip_atomic_store(&flags[bb*NKER + t], 0u, __ATOMIC_RELEASE, __HIP_MEMORY_SCOPE_AGENT);

    if (t < UNITS*UNITS) {
        const int u = t / UNITS, v = t - u*UNITS;
        float a = s_[t];
        if (u == v) a += sp2[u]*(s_[PART-2] + s_[PART-1]);
        s4[t] = a;
    }
    if (t == 128) {   // softmax(mu4) on an idle lane
        float mx = s_[100];
        #pragma unroll
        for (int u = 1; u < UNITS; ++u) mx = fmaxf(mx, s_[100+u]);
        float sum = 0.f;
        float e[UNITS];
        #pragma unroll
        for (int u = 0; u < UNITS; ++u) { e[u] = expf(s_[100+u] - mx); sum += e[u]; }
        #pragma unroll
        for (int u = 0; u < UNITS; ++u) p_s[u] = e[u] / sum;
    }
    __syncthreads();

    // sigma_out = G s4 G^T, G = diag(p) - p p^T
    if (t < UNITS) {
        float r = 0.f;
        #pragma unroll
        for (int j = 0; j < UNITS; ++j) r = fmaf(p_s[j], s4[j*UNITS + t], r);
        r_s[t] = r;
    }
    __syncthreads();
    if (t < UNITS*UNITS) {
        const int i = t / UNITS, k2 = t - i*UNITS;
        tmp[t] = p_s[i]*(s4[t] - r_s[k2]);
    }
    __syncthreads();
    if (t < UNITS) {
        float q = 0.f;
        #pragma unroll
        for (int kk = 0; kk < UNITS; ++kk) q = fmaf(tmp[t*UNITS + kk], p_s[kk], q);
        q_s[t] = q;
    }
    __syncthreads();
    if (t < UNITS*UNITS) {
        const int i = t / UNITS, l = t - i*UNITS;
        out[BATCH*UNITS + bb*UNITS*UNITS + t] = p_s[l]*(tmp[i*UNITS + l] - q_s[i]);
    }
    if (t < UNITS) out[bb*UNITS + t] = p_s[t];
}

extern "C" void kernel_launch(void* const* d_in, const int* in_sizes, int n_in,
                              void* d_out, int out_size, void* d_ws, size_t ws_size,
                              hipStream_t stream) {
    const float* x      = (const float*)d_in[0];
    const float* conv_w = (const float*)d_in[1];
    const float* conv_s = (const float*)d_in[2];
    const float* fc_w   = (const float*)d_in[3];
    const float* fc_s   = (const float*)d_in[4];
    float* out = (float*)d_out;
    float* ws  = (float*)d_ws;                              // 256*PART floats
    unsigned int* flags = (unsigned int*)((char*)d_ws + BATCH*NKER*PART*sizeof(float));

    vdp_fused<<<BATCH*NKER, 256, 0, stream>>>(x, conv_w, conv_s, fc_w, fc_s,
                                              out, ws, flags);
}

// Round 6
// 27.899 us; speedup vs baseline: 2.5481x; 1.2164x over previous
//
#include <hip/hip_runtime.h>
#include <math.h>

#define BATCH 16
#define NKER  16
#define KS    5
#define UNITS 10
#define HIN   28
#define HOUT  24       // 28-5+1
#define PO    12       // pooled 12x12
#define NPOOL (PO*PO)  // 144
#define NC    (KS*KS)  // 25 patch channels
#define NCELL (NKER*NPOOL)   // 2304
#define XSZ   928      // 784 image + zero pad region (reads from idx=784 land here)
#define TPAD  28       // padded T columns (25 real + 3 scratch)

// Single dispatch, 16 independent blocks (one per batch element), 1024 threads.
// No workspace, no cross-block communication (XCD-coherence-free).
__global__ __launch_bounds__(1024) void vdp_one(
    const float* __restrict__ x,       // [B,1,28,28]
    const float* __restrict__ conv_w,  // [K,1,5,5]
    const float* __restrict__ conv_s,  // [K]
    const float* __restrict__ fc_w,    // [2304,10]
    const float* __restrict__ fc_s,    // [10]
    float* __restrict__ out)           // [B*10] p ++ [B*100] sigma_out
{
    const int b = blockIdx.x;
    const int t = threadIdx.x;

    __shared__ float xs[XSZ];              // image + zero pad
    __shared__ float cw[NKER*NC];          // all conv weights
    __shared__ float sp1[NKER];
    __shared__ float sp2[UNITS];
    __shared__ short idx_s[NCELL];         // argmax window base (784 if gated off)
    __shared__ float T_s[NKER][UNITS][TPAD];
    __shared__ float A_s[NKER][UNITS*UNITS];
    __shared__ float red_s[16][12];
    __shared__ float fin_s[12];            // [tr(sp1-weighted), mn, mu4[10]]
    __shared__ float s_[UNITS*UNITS];
    __shared__ float s4[UNITS*UNITS];
    __shared__ float tmp[UNITS*UNITS];
    __shared__ float p_s[UNITS], r_s[UNITS], q_s[UNITS];

    // ---- staging ----
    {
        const float4* x4 = reinterpret_cast<const float4*>(x + b*HIN*HIN);
        float4* xs4 = reinterpret_cast<float4*>(xs);
        if (t < HIN*HIN/4) xs4[t] = x4[t];                 // 196
        if (t >= 784 && t < XSZ) xs[t] = 0.f;              // zero pad region
        if (t >= 512 && t < 512 + NKER*NC) cw[t-512] = conv_w[t-512];
        if (t < NKER) sp1[t] = log1pf(expf(conv_s[t]));
        if (t >= 32 && t < 32 + UNITS) sp2[t-32] = log1pf(expf(fc_s[t-32]));
    }
    __syncthreads();

    // ---- phase 1: conv + relu + argmax-pool for all (k, pooled cell) ----
    float v_tr = 0.f, v_mn = 0.f;
    float v_mu[UNITS];
    #pragma unroll
    for (int u = 0; u < UNITS; ++u) v_mu[u] = 0.f;

    for (int cell = t; cell < NCELL; cell += 1024) {
        const int k  = cell / NPOOL;
        const int m  = cell - k*NPOOL;
        const int pi = m / PO, pj = m - pi*PO;
        float w6[36];
        #pragma unroll
        for (int r = 0; r < 6; ++r)
            #pragma unroll
            for (int cc = 0; cc < 6; ++cc)
                w6[r*6 + cc] = xs[(2*pi + r)*HIN + 2*pj + cc];

        float a0 = 0.f, a1 = 0.f, a2 = 0.f, a3 = 0.f;
        #pragma unroll
        for (int kh = 0; kh < KS; ++kh)
            #pragma unroll
            for (int kw = 0; kw < KS; ++kw) {
                const float w = cw[k*NC + kh*KS + kw];
                a0 = fmaf(w, w6[kh*6 + kw],       a0);
                a1 = fmaf(w, w6[kh*6 + kw + 1],   a1);
                a2 = fmaf(w, w6[(kh+1)*6 + kw],   a2);
                a3 = fmaf(w, w6[(kh+1)*6 + kw+1], a3);
            }
        const float r0 = fmaxf(a0, 0.f), r1 = fmaxf(a1, 0.f);
        const float r2 = fmaxf(a2, 0.f), r3 = fmaxf(a3, 0.f);
        float bestv = r0; int besta = 0;                   // first-max wins (jnp.argmax)
        if (r1 > bestv) { bestv = r1; besta = 1; }
        if (r2 > bestv) { bestv = r2; besta = 2; }
        if (r3 > bestv) { bestv = r3; besta = 3; }
        const float mu3 = bestv;
        const float g   = (mu3 > 0.f) ? 1.f : 0.f;

        // selected raw patch: norm for trace term (branch-free select)
        float ns = 0.f;
        #pragma unroll
        for (int kh = 0; kh < KS; ++kh)
            #pragma unroll
            for (int kw = 0; kw < KS; ++kw) {
                const float v0 = w6[kh*6 + kw];
                const float v1 = w6[kh*6 + kw + 1];
                const float v2 = w6[(kh+1)*6 + kw];
                const float v3 = w6[(kh+1)*6 + kw + 1];
                const float val = (besta < 2) ? ((besta == 0) ? v0 : v1)
                                              : ((besta == 2) ? v2 : v3);
                ns = fmaf(val, val, ns);
            }
        const int oh = 2*pi + (besta >> 1);
        const int ow = 2*pj + (besta & 1);
        idx_s[cell] = (short)((g > 0.f) ? (oh*HIN + ow) : 784);  // 784 -> zero region

        v_tr = fmaf(g*sp1[k], ns, v_tr);
        v_mn = fmaf(mu3, mu3, v_mn);
        const float* fr = fc_w + cell*UNITS;               // coalesced across threads
        #pragma unroll
        for (int u = 0; u < UNITS; ++u) v_mu[u] = fmaf(mu3, fr[u], v_mu[u]);
    }

    // ---- deterministic reduce of 12 values over 16 waves ----
    {
        float vals[12];
        vals[0] = v_tr; vals[1] = v_mn;
        #pragma unroll
        for (int u = 0; u < UNITS; ++u) vals[2+u] = v_mu[u];
        #pragma unroll
        for (int off = 32; off >= 1; off >>= 1)
            #pragma unroll
            for (int j = 0; j < 12; ++j)
                vals[j] += __shfl_down(vals[j], off);
        const int wid = t >> 6, lane = t & 63;
        if (lane == 0)
            #pragma unroll
            for (int j = 0; j < 12; ++j) red_s[wid][j] = vals[j];
    }
    __syncthreads();
    if (t < 12) {
        float a = 0.f;
        #pragma unroll
        for (int w = 0; w < 16; ++w) a += red_s[w][t];
        fin_s[t] = a;
    }

    // ---- phase 2: T[k,u,c] = sum_i fcw[k,i,u] * xs[idx[k,i] + off(c)] ----
    // wave = k; lane: iq=lane&7 (i-chunk of 18), ch=(lane>>3)&3 (7 c's), uh=lane>>5 (5 u's)
    {
        const int k  = t >> 6;
        const int ln = t & 63;
        const int iq = ln & 7;
        const int ch = (ln >> 3) & 3;
        const int uh = ln >> 5;
        const int u0 = uh*5;
        const int c0 = ch*7;
        int off_c[7];
        #pragma unroll
        for (int cc = 0; cc < 7; ++cc) {
            const int c = c0 + cc;
            const int kh = c / KS, kw = c - kh*KS;
            off_c[cc] = kh*HIN + kw;
        }
        float acc[5][7];
        #pragma unroll
        for (int uu = 0; uu < 5; ++uu)
            #pragma unroll
            for (int cc = 0; cc < 7; ++cc) acc[uu][cc] = 0.f;

        const int ibase = k*NPOOL + iq*18;
        #pragma unroll 3
        for (int ii = 0; ii < 18; ++ii) {
            const int base = idx_s[ibase + ii];
            const float* wp = fc_w + (ibase + ii)*UNITS + u0;
            float wv[5];
            #pragma unroll
            for (int uu = 0; uu < 5; ++uu) wv[uu] = wp[uu];
            float pv[7];
            #pragma unroll
            for (int cc = 0; cc < 7; ++cc) pv[cc] = xs[base + off_c[cc]];
            #pragma unroll
            for (int uu = 0; uu < 5; ++uu)
                #pragma unroll
                for (int cc = 0; cc < 7; ++cc)
                    acc[uu][cc] = fmaf(wv[uu], pv[cc], acc[uu][cc]);
        }
        // reduce over the 8 i-chunks (lanes iq=0..7 within each 8-lane segment)
        #pragma unroll
        for (int off = 4; off >= 1; off >>= 1)
            #pragma unroll
            for (int uu = 0; uu < 5; ++uu)
                #pragma unroll
                for (int cc = 0; cc < 7; ++cc)
                    acc[uu][cc] += __shfl_down(acc[uu][cc], off, 8);
        if (iq == 0)
            #pragma unroll
            for (int uu = 0; uu < 5; ++uu)
                #pragma unroll
                for (int cc = 0; cc < 7; ++cc)
                    T_s[k][u0+uu][c0+cc] = acc[uu][cc];
    }
    __syncthreads();

    // ---- phase 3: A[k,u,v] = sp1[k] * sum_{c<25} T[k,u,c]*T[k,v,c] ----
    for (int task = t; task < NKER*UNITS*UNITS; task += 1024) {
        const int k2 = task / (UNITS*UNITS);
        const int uv = task - k2*(UNITS*UNITS);
        const int u = uv / UNITS, v = uv - u*UNITS;
        float s = 0.f;
        #pragma unroll
        for (int c = 0; c < NC; ++c) s = fmaf(T_s[k2][u][c], T_s[k2][v][c], s);
        A_s[k2][uv] = sp1[k2]*s;
    }
    if (t == 1023) {   // softmax(mu4) in parallel (fin_s ready since last sync)
        float mx = fin_s[2];
        #pragma unroll
        for (int u = 1; u < UNITS; ++u) mx = fmaxf(mx, fin_s[2+u]);
        float sum = 0.f;
        float e[UNITS];
        #pragma unroll
        for (int u = 0; u < UNITS; ++u) { e[u] = expf(fin_s[2+u] - mx); sum += e[u]; }
        #pragma unroll
        for (int u = 0; u < UNITS; ++u) p_s[u] = e[u] / sum;
    }
    __syncthreads();

    // ---- finale ----
    if (t < UNITS*UNITS) {
        float a = 0.f;
        #pragma unroll
        for (int k = 0; k < NKER; ++k) a += A_s[k][t];
        s_[t] = a;
        const int u = t / UNITS, v = t - u*UNITS;
        float s4v = a;
        if (u == v) s4v += sp2[u]*(fin_s[0] + fin_s[1]);
        s4[t] = s4v;
    }
    __syncthreads();
    if (t < UNITS) {
        float r = 0.f;
        #pragma unroll
        for (int j = 0; j < UNITS; ++j) r = fmaf(p_s[j], s4[j*UNITS + t], r);
        r_s[t] = r;
    }
    __syncthreads();
    if (t < UNITS*UNITS) {
        const int i = t / UNITS, k2 = t - i*UNITS;
        tmp[t] = p_s[i]*(s4[t] - r_s[k2]);
    }
    __syncthreads();
    if (t < UNITS) {
        float q = 0.f;
        #pragma unroll
        for (int kk = 0; kk < UNITS; ++kk) q = fmaf(tmp[t*UNITS + kk], p_s[kk], q);
        q_s[t] = q;
    }
    __syncthreads();
    if (t < UNITS*UNITS) {
        const int i = t / UNITS, l = t - i*UNITS;
        out[BATCH*UNITS + b*UNITS*UNITS + t] = p_s[l]*(tmp[i*UNITS + l] - q_s[i]);
    }
    if (t < UNITS) out[b*UNITS + t] = p_s[t];
}

extern "C" void kernel_launch(void* const* d_in, const int* in_sizes, int n_in,
                              void* d_out, int out_size, void* d_ws, size_t ws_size,
                              hipStream_t stream) {
    const float* x      = (const float*)d_in[0];
    const float* conv_w = (const float*)d_in[1];
    const float* conv_s = (const float*)d_in[2];
    const float* fc_w   = (const float*)d_in[3];
    const float* fc_s   = (const float*)d_in[4];
    float* out = (float*)d_out;
    vdp_one<<<BATCH, 1024, 0, stream>>>(x, conv_w, conv_s, fc_w, fc_s, out);
}

// Round 8
// 27.382 us; speedup vs baseline: 2.5963x; 1.0189x over previous
//
#include <hip/hip_runtime.h>
#include <math.h>

#define BATCH 16
#define NKER  16
#define KS    5
#define UNITS 10
#define HIN   28
#define PO    12
#define NPOOL (PO*PO)        // 144
#define NC    (KS*KS)        // 25
#define NCELL (NKER*NPOOL)   // 2304
#define XSZ   928            // 784 image + zero pad (gated gathers land here)
#define TPAD  28             // padded T columns (25 real + 3 scratch)

// Single dispatch, 16 independent blocks (one per batch element), 512 threads.
// No workspace, no cross-block communication.
__global__ __launch_bounds__(512, 2) void vdp_one(
    const float* __restrict__ x,       // [B,1,28,28]
    const float* __restrict__ conv_w,  // [K,1,5,5]
    const float* __restrict__ conv_s,  // [K]
    const float* __restrict__ fc_w,    // [2304,10]
    const float* __restrict__ fc_s,    // [10]
    float* __restrict__ out)           // [B*10] p ++ [B*100] sigma_out
{
    const int b = blockIdx.x;
    const int t = threadIdx.x;

    __shared__ float xs[XSZ];
    __shared__ float cw[NKER*NC];
    __shared__ float sp1[NKER];
    __shared__ float sp2[UNITS];
    __shared__ short idx_s[NCELL];         // argmax window base (784 if gated off)
    __shared__ float T_s[NKER][UNITS][TPAD];
    __shared__ float A_s[NKER][UNITS*UNITS];
    __shared__ float red_s[8][12];
    __shared__ float fin_s[12];            // [tr(sp1-weighted), mn, mu4[10]]
    __shared__ float s4[UNITS*UNITS];
    __shared__ float tmp[UNITS*UNITS];
    __shared__ float p_s[UNITS], r_s[UNITS], q_s[UNITS];

    // ---- staging (all ranges valid for 512 threads!) ----
    {
        const float4* x4 = reinterpret_cast<const float4*>(x + b*HIN*HIN);
        float4* xs4 = reinterpret_cast<float4*>(xs);
        if (t < HIN*HIN/4) xs4[t] = x4[t];                       // 196 float4s
        if (t >= 196 && t < 196 + (XSZ - 784)) xs[784 + t-196] = 0.f;  // pad [784,928)
        for (int i = t; i < NKER*NC; i += 512) cw[i] = conv_w[i];      // all 400!
        if (t < NKER) sp1[t] = log1pf(expf(conv_s[t]));
        if (t >= 480 && t < 480 + UNITS) sp2[t-480] = log1pf(expf(fc_s[t-480]));
    }
    __syncthreads();

    // ---- phase 1: conv + relu + argmax-pool. wave w: k=2w,2w+1; lane j<48: 3 cells each ----
    float v_tr = 0.f, v_mn = 0.f;
    float v_mu[UNITS];
    #pragma unroll
    for (int u = 0; u < UNITS; ++u) v_mu[u] = 0.f;

    {
        const int wv = t >> 6;     // 0..7
        const int j  = t & 63;
        if (j < 48) {
            #pragma unroll
            for (int kk = 0; kk < 2; ++kk) {
                const int k = 2*wv + kk;
                const float sp1k = sp1[k];
                float cwr[NC];
                #pragma unroll
                for (int c = 0; c < NC; ++c) cwr[c] = cw[k*NC + c];
                #pragma unroll
                for (int ml = 0; ml < 3; ++ml) {
                    const int m  = j + 48*ml;
                    const int pi = m / PO, pj = m - pi*PO;
                    float w6[36];                      // aligned float2 loads
                    #pragma unroll
                    for (int r = 0; r < 6; ++r)
                        #pragma unroll
                        for (int c2 = 0; c2 < 3; ++c2) {
                            const float2 v2 = *reinterpret_cast<const float2*>(
                                &xs[(2*pi + r)*HIN + 2*pj + 2*c2]);
                            w6[r*6 + 2*c2]     = v2.x;
                            w6[r*6 + 2*c2 + 1] = v2.y;
                        }
                    float a0 = 0.f, a1 = 0.f, a2 = 0.f, a3 = 0.f;
                    #pragma unroll
                    for (int kh = 0; kh < KS; ++kh)
                        #pragma unroll
                        for (int kw = 0; kw < KS; ++kw) {
                            const float w = cwr[kh*KS + kw];
                            a0 = fmaf(w, w6[kh*6 + kw],       a0);
                            a1 = fmaf(w, w6[kh*6 + kw + 1],   a1);
                            a2 = fmaf(w, w6[(kh+1)*6 + kw],   a2);
                            a3 = fmaf(w, w6[(kh+1)*6 + kw+1], a3);
                        }
                    const float r0 = fmaxf(a0, 0.f), r1 = fmaxf(a1, 0.f);
                    const float r2 = fmaxf(a2, 0.f), r3 = fmaxf(a3, 0.f);
                    float bestv = r0; int besta = 0;   // first-max wins (jnp.argmax)
                    if (r1 > bestv) { bestv = r1; besta = 1; }
                    if (r2 > bestv) { bestv = r2; besta = 2; }
                    if (r3 > bestv) { bestv = r3; besta = 3; }
                    const float mu3 = bestv;
                    const float g   = (mu3 > 0.f) ? 1.f : 0.f;

                    float ns = 0.f;                    // ||selected patch||^2
                    #pragma unroll
                    for (int kh = 0; kh < KS; ++kh)
                        #pragma unroll
                        for (int kw = 0; kw < KS; ++kw) {
                            const float v0 = w6[kh*6 + kw];
                            const float v1 = w6[kh*6 + kw + 1];
                            const float v2 = w6[(kh+1)*6 + kw];
                            const float v3 = w6[(kh+1)*6 + kw + 1];
                            const float val = (besta < 2) ? ((besta == 0) ? v0 : v1)
                                                          : ((besta == 2) ? v2 : v3);
                            ns = fmaf(val, val, ns);
                        }
                    const int oh = 2*pi + (besta >> 1);
                    const int ow = 2*pj + (besta & 1);
                    const int cell = k*NPOOL + m;
                    idx_s[cell] = (short)((g > 0.f) ? (oh*HIN + ow) : 784);

                    v_tr = fmaf(g*sp1k, ns, v_tr);
                    v_mn = fmaf(mu3, mu3, v_mn);
                    const float* fr = fc_w + cell*UNITS;   // 8B-aligned (40B rows)
                    #pragma unroll
                    for (int uu = 0; uu < 5; ++uu) {
                        const float2 f2 = *reinterpret_cast<const float2*>(&fr[2*uu]);
                        v_mu[2*uu]   = fmaf(mu3, f2.x, v_mu[2*uu]);
                        v_mu[2*uu+1] = fmaf(mu3, f2.y, v_mu[2*uu+1]);
                    }
                }
            }
        }
    }

    // ---- deterministic reduce of 12 values over 8 waves ----
    {
        float vals[12];
        vals[0] = v_tr; vals[1] = v_mn;
        #pragma unroll
        for (int u = 0; u < UNITS; ++u) vals[2+u] = v_mu[u];
        #pragma unroll
        for (int off = 32; off >= 1; off >>= 1)
            #pragma unroll
            for (int jj = 0; jj < 12; ++jj)
                vals[jj] += __shfl_down(vals[jj], off);
        if ((t & 63) == 0)
            #pragma unroll
            for (int jj = 0; jj < 12; ++jj) red_s[t >> 6][jj] = vals[jj];
    }
    __syncthreads();
    if (t < 12) {
        float a = 0.f;
        #pragma unroll
        for (int w = 0; w < 8; ++w) a += red_s[w][t];
        fin_s[t] = a;
    }

    // ---- phase 2: T[k,u,c] = sum_i fcw[k,i,u] * xs[idx[k,i] + off(c)] ----
    // half-wave h = k; lane l<32: iq=l&3 (4 i-chunks of 36), ch=(l>>2)&3 (7 c), uh=l>>4 (5 u)
    {
        const int h  = t >> 5;
        const int l  = t & 31;
        const int iq = l & 3;
        const int ch = (l >> 2) & 3;
        const int uh = l >> 4;
        const int u0 = uh*5, c0 = ch*7;
        int off_c[7];
        #pragma unroll
        for (int cc = 0; cc < 7; ++cc) {
            const int c = c0 + cc;
            off_c[cc] = (c/KS)*HIN + (c - (c/KS)*KS);
        }
        float acc[5][7];
        #pragma unroll
        for (int uu = 0; uu < 5; ++uu)
            #pragma unroll
            for (int cc = 0; cc < 7; ++cc) acc[uu][cc] = 0.f;

        const int ibase = h*NPOOL + iq*36;
        #pragma unroll 4
        for (int ii = 0; ii < 36; ++ii) {
            const int base = idx_s[ibase + ii];
            const float* wp = fc_w + (ibase + ii)*UNITS + u0;
            float wvv[5];
            #pragma unroll
            for (int uu = 0; uu < 5; ++uu) wvv[uu] = wp[uu];
            float pv[7];
            #pragma unroll
            for (int cc = 0; cc < 7; ++cc) pv[cc] = xs[base + off_c[cc]];
            #pragma unroll
            for (int uu = 0; uu < 5; ++uu)
                #pragma unroll
                for (int cc = 0; cc < 7; ++cc)
                    acc[uu][cc] = fmaf(wvv[uu], pv[cc], acc[uu][cc]);
        }
        #pragma unroll
        for (int off = 2; off >= 1; off >>= 1)
            #pragma unroll
            for (int uu = 0; uu < 5; ++uu)
                #pragma unroll
                for (int cc = 0; cc < 7; ++cc)
                    acc[uu][cc] += __shfl_down(acc[uu][cc], off, 4);
        if (iq == 0)
            #pragma unroll
            for (int uu = 0; uu < 5; ++uu)
                #pragma unroll
                for (int cc = 0; cc < 7; ++cc)
                    T_s[h][u0+uu][c0+cc] = acc[uu][cc];
    }
    __syncthreads();

    // ---- phase 3: A[k,u,v] = sp1[k] * sum_{c<25} T[k,u,c]*T[k,v,c]; softmax in parallel ----
    for (int task = t; task < NKER*UNITS*UNITS; task += 512) {
        const int k2 = task / (UNITS*UNITS);
        const int uv = task - k2*(UNITS*UNITS);
        const int u = uv / UNITS, v = uv - u*UNITS;
        float s = 0.f;
        #pragma unroll
        for (int c = 0; c < NC; ++c) s = fmaf(T_s[k2][u][c], T_s[k2][v][c], s);
        A_s[k2][uv] = sp1[k2]*s;
    }
    if (t == 511) {
        float mx = fin_s[2];
        #pragma unroll
        for (int u = 1; u < UNITS; ++u) mx = fmaxf(mx, fin_s[2+u]);
        float sum = 0.f;
        float e[UNITS];
        #pragma unroll
        for (int u = 0; u < UNITS; ++u) { e[u] = expf(fin_s[2+u] - mx); sum += e[u]; }
        #pragma unroll
        for (int u = 0; u < UNITS; ++u) p_s[u] = e[u] / sum;
    }
    __syncthreads();

    // ---- finale ----
    if (t < UNITS*UNITS) {
        float a = 0.f;
        #pragma unroll
        for (int k = 0; k < NKER; ++k) a += A_s[k][t];
        const int u = t / UNITS, v = t - u*UNITS;
        float s4v = a;
        if (u == v) s4v += sp2[u]*(fin_s[0] + fin_s[1]);
        s4[t] = s4v;
    }
    __syncthreads();
    if (t < UNITS) {
        float r = 0.f;
        #pragma unroll
        for (int jj = 0; jj < UNITS; ++jj) r = fmaf(p_s[jj], s4[jj*UNITS + t], r);
        r_s[t] = r;
    }
    __syncthreads();
    if (t < UNITS*UNITS) {
        const int i = t / UNITS, k2 = t - i*UNITS;
        tmp[t] = p_s[i]*(s4[t] - r_s[k2]);
    }
    __syncthreads();
    if (t < UNITS) {
        float q = 0.f;
        #pragma unroll
        for (int kk = 0; kk < UNITS; ++kk) q = fmaf(tmp[t*UNITS + kk], p_s[kk], q);
        q_s[t] = q;
    }
    __syncthreads();
    if (t < UNITS*UNITS) {
        const int i = t / UNITS, l = t - i*UNITS;
        out[BATCH*UNITS + b*UNITS*UNITS + t] = p_s[l]*(tmp[i*UNITS + l] - q_s[i]);
    }
    if (t < UNITS) out[b*UNITS + t] = p_s[t];
}

extern "C" void kernel_launch(void* const* d_in, const int* in_sizes, int n_in,
                              void* d_out, int out_size, void* d_ws, size_t ws_size,
                              hipStream_t stream) {
    const float* x      = (const float*)d_in[0];
    const float* conv_w = (const float*)d_in[1];
    const float* conv_s = (const float*)d_in[2];
    const float* fc_w   = (const float*)d_in[3];
    const float* fc_s   = (const float*)d_in[4];
    float* out = (float*)d_out;
    vdp_one<<<BATCH, 512, 0, stream>>>(x, conv_w, conv_s, fc_w, fc_s, out);
}